// Round 9
// baseline (728.298 us; speedup 1.0000x reference)
//
#include <hip/hip_runtime.h>
#include <hip/hip_bf16.h>
#include <hip/hip_fp16.h>
#include <math.h>

#define NROW 16384
#define DIN 32

typedef _Float16 f16x8 __attribute__((ext_vector_type(8)));
typedef float f32x4 __attribute__((ext_vector_type(4)));

constexpr int MM_KSEG = 16;
constexpr int MM_SEGK = NROW / MM_KSEG;   // 1024 k per segment
constexpr int MM_KSTEPS = MM_SEGK / 32;   // 32 mfma K-steps per segment
constexpr int KMAX = 4;                   // Chebyshev truncation (|a_hp[5]|=1.0e-3)

// ---------------------------------------------------------------------------
// Fragment-packed Lh layout, 2 fragments (32 rows) per k-step group:
//   fragment = 16 rows x 32 cols = 64 lanes x 8 halfs = 1 KB contiguous.
//   order: [g32 = i/32][kseg][s = k-step][t2 = i-tile-of-16 (0,1)][lane][8]
// passH wave (32 rows) streams one (g32,kseg) = 64 KB sequentially.
// B-layout (Thp/Xp): Bp[k>>3][j][k&7]; lane l reads 8 contiguous halfs at
// Bp[((kb>>3)+(l>>4))*256 + (jt*16 + (l&15))*8].
// D (verified m89): row=(l>>4)*4+reg, col=l&15.
// ---------------------------------------------------------------------------
constexpr size_t FRAG_H  = 512;                      // halfs per fragment (1 KB)
constexpr size_t STEP2_H = 2 * FRAG_H;               // 2 i-tiles per step
constexpr size_t WSEG2_H = (size_t)MM_KSTEPS * STEP2_H;  // per (g32,kseg): 32Ki halfs

// pack X (fp32 [k][32]) -> Xp fp16 packed B-layout. One float4 per thread.
__global__ __launch_bounds__(256)
void pack_x(const float* __restrict__ X, _Float16* __restrict__ Xp)
{
    const int g = blockIdx.x * 256 + threadIdx.x;   // float4 index
    const int k = g >> 3, q = g & 7, j0 = q * 4;
    float4 v = ((const float4*)X)[g];
    _Float16* tp = Xp + (size_t)(k >> 3) * 256 + (k & 7);
    tp[(j0 + 0) * 8] = (_Float16)v.x;
    tp[(j0 + 1) * 8] = (_Float16)v.y;
    tp[(j0 + 2) * 8] = (_Float16)v.z;
    tp[(j0 + 3) * 8] = (_Float16)v.w;
}

// ---------------------------------------------------------------------------
// Pass 1: Yp[seg] = L(fp32) @ Xp; emit Lh = fp16(L) fragment-packed in the
// 2-tile-grouped layout. Block 256 = 4 waves; wave covers 64 rows (4 i-tiles
// = two g32 groups). fp32-read-bound; keeps 4-tile shape.
// ---------------------------------------------------------------------------
__global__ __launch_bounds__(256)
void mm_pass1(const float* __restrict__ L, const _Float16* __restrict__ Xp,
              float* __restrict__ Yp, _Float16* __restrict__ Lh)
{
    const int wave = threadIdx.x >> 6, lane = threadIdx.x & 63;
    const int gr = lane >> 4, m = lane & 15;
    const int i0 = blockIdx.x * 256 + wave * 64;
    const int kseg = blockIdx.y;
    const int kb0 = kseg * MM_SEGK;
    const int g32 = i0 >> 5;                         // first of two g32 groups

    f32x4 acc[4][2];
#pragma unroll
    for (int t = 0; t < 4; ++t) { acc[t][0] = (f32x4)0.f; acc[t][1] = (f32x4)0.f; }

    const float*  ap = L  + (size_t)(i0 + m) * NROW + kb0 + gr * 8;
    _Float16* sp0 = Lh + ((size_t)(g32 + 0) * MM_KSEG + kseg) * WSEG2_H + (size_t)lane * 8;
    _Float16* sp1 = Lh + ((size_t)(g32 + 1) * MM_KSEG + kseg) * WSEG2_H + (size_t)lane * 8;
    const _Float16* bp = Xp + ((size_t)(kb0 >> 3) + gr) * 256 + m * 8;

    for (int s = 0; s < MM_KSTEPS; ++s) {
        f16x8 b0 = *(const f16x8*)(bp);
        f16x8 b1 = *(const f16x8*)(bp + 128);
        bp += 1024;
#pragma unroll
        for (int t = 0; t < 4; ++t) {
            const float* a32 = ap + (size_t)t * 16 * NROW;
            f32x4 u = __builtin_nontemporal_load((const f32x4*)a32);
            f32x4 v = __builtin_nontemporal_load((const f32x4*)(a32 + 4));
            f16x8 a;
            a[0] = (_Float16)u[0]; a[1] = (_Float16)u[1];
            a[2] = (_Float16)u[2]; a[3] = (_Float16)u[3];
            a[4] = (_Float16)v[0]; a[5] = (_Float16)v[1];
            a[6] = (_Float16)v[2]; a[7] = (_Float16)v[3];
            _Float16* sp = (t < 2) ? sp0 : sp1;
            __builtin_nontemporal_store(a, (f16x8*)(sp + (t & 1) * FRAG_H));
            acc[t][0] = __builtin_amdgcn_mfma_f32_16x16x32_f16(a, b0, acc[t][0], 0, 0, 0);
            acc[t][1] = __builtin_amdgcn_mfma_f32_16x16x32_f16(a, b1, acc[t][1], 0, 0, 0);
        }
        ap += 32; sp0 += STEP2_H; sp1 += STEP2_H;
    }

#pragma unroll
    for (int t = 0; t < 4; ++t)
#pragma unroll
        for (int jt = 0; jt < 2; ++jt) {
            const int row = i0 + t * 16 + gr * 4;
            float* yb = Yp + ((size_t)kseg * NROW + row) * DIN + jt * 16 + m;
#pragma unroll
            for (int r = 0; r < 4; ++r) yb[(size_t)r * DIN] = acc[t][jt][r];
        }
}

// ---------------------------------------------------------------------------
// Passes 2..KMAX: Yp[seg] = Lh(packed fp16) @ Thp. Wave owns 32 rows
// (2 i-tiles): acc 16 VGPR -> target <=64 VGPR, 8 waves/SIMD (launch_bounds
// min-waves-per-EU = 8). Grid (128, KSEG) = 2048 blocks = 8 blocks/CU.
// ---------------------------------------------------------------------------
__global__ __launch_bounds__(256, 8)
void mm_passH(const _Float16* __restrict__ Lh, const _Float16* __restrict__ Thp,
              float* __restrict__ Yp)
{
    const int wave = threadIdx.x >> 6, lane = threadIdx.x & 63;
    const int gr = lane >> 4, m = lane & 15;
    const int i0 = blockIdx.x * 128 + wave * 32;
    const int kseg = blockIdx.y;
    const int kb0 = kseg * MM_SEGK;
    const int g32 = i0 >> 5;

    f32x4 acc[2][2];
    acc[0][0] = (f32x4)0.f; acc[0][1] = (f32x4)0.f;
    acc[1][0] = (f32x4)0.f; acc[1][1] = (f32x4)0.f;

    const _Float16* ap = Lh + ((size_t)g32 * MM_KSEG + kseg) * WSEG2_H + (size_t)lane * 8;
    const _Float16* bp = Thp + ((size_t)(kb0 >> 3) + gr) * 256 + m * 8;

    for (int s = 0; s < MM_KSTEPS; ++s) {
        f16x8 b0 = *(const f16x8*)(bp);
        f16x8 b1 = *(const f16x8*)(bp + 128);
        bp += 1024;
        f16x8 a0 = __builtin_nontemporal_load((const f16x8*)(ap));
        f16x8 a1 = __builtin_nontemporal_load((const f16x8*)(ap + FRAG_H));
        ap += STEP2_H;
        acc[0][0] = __builtin_amdgcn_mfma_f32_16x16x32_f16(a0, b0, acc[0][0], 0, 0, 0);
        acc[0][1] = __builtin_amdgcn_mfma_f32_16x16x32_f16(a0, b1, acc[0][1], 0, 0, 0);
        acc[1][0] = __builtin_amdgcn_mfma_f32_16x16x32_f16(a1, b0, acc[1][0], 0, 0, 0);
        acc[1][1] = __builtin_amdgcn_mfma_f32_16x16x32_f16(a1, b1, acc[1][1], 0, 0, 0);
    }

#pragma unroll
    for (int t = 0; t < 2; ++t)
#pragma unroll
        for (int jt = 0; jt < 2; ++jt) {
            const int row = i0 + t * 16 + gr * 4;
            float* yb = Yp + ((size_t)kseg * NROW + row) * DIN + jt * 16 + m;
#pragma unroll
            for (int r = 0; r < 4; ++r) yb[(size_t)r * DIN] = acc[t][jt][r];
        }
}

// ---------------------------------------------------------------------------
// Sum MM_KSEG partials -> Y; Chebyshev recurrence + LP/HPc accumulation;
// also emit next T packed to fp16 (Thp) for the following MFMA pass.
// ---------------------------------------------------------------------------
__global__ __launch_bounds__(256)
void cheb_epilogue(const float* __restrict__ Yp, const float* __restrict__ X,
                   const float* __restrict__ Tprev, float* __restrict__ Tnext,
                   _Float16* __restrict__ Thp,
                   float* __restrict__ LP, float* __restrict__ HPc,
                   float cl, float ch, float cl0, float ch0, int first)
{
    const int g = blockIdx.x * 256 + threadIdx.x;   // float4 index
    const size_t stride = (size_t)NROW * DIN / 4;   // 131072

    float4 y = make_float4(0.f, 0.f, 0.f, 0.f);
#pragma unroll
    for (int s = 0; s < MM_KSEG; ++s) {
        float4 p = ((const float4*)Yp)[s * stride + g];
        y.x += p.x; y.y += p.y; y.z += p.z; y.w += p.w;
    }

    float4 t;
    if (first) {
        float4 x = ((const float4*)X)[g];
        t = y;
        ((float4*)LP)[g]  = make_float4(cl0 * x.x + cl * y.x, cl0 * x.y + cl * y.y,
                                        cl0 * x.z + cl * y.z, cl0 * x.w + cl * y.w);
        ((float4*)HPc)[g] = make_float4(ch0 * x.x + ch * y.x, ch0 * x.y + ch * y.y,
                                        ch0 * x.z + ch * y.z, ch0 * x.w + ch * y.w);
    } else {
        float4 tp = ((const float4*)Tprev)[g];
        t = make_float4(2.f * y.x - tp.x, 2.f * y.y - tp.y,
                        2.f * y.z - tp.z, 2.f * y.w - tp.w);
        float4 l = ((float4*)LP)[g];
        l.x += cl * t.x; l.y += cl * t.y; l.z += cl * t.z; l.w += cl * t.w;
        ((float4*)LP)[g] = l;
        float4 h = ((float4*)HPc)[g];
        h.x += ch * t.x; h.y += ch * t.y; h.z += ch * t.z; h.w += ch * t.w;
        ((float4*)HPc)[g] = h;
    }
    ((float4*)Tnext)[g] = t;

    // pack T -> fp16 B-layout for the next MFMA pass
    const int k = g >> 3, q = g & 7, j0 = q * 4;
    _Float16* tp16 = Thp + (size_t)(k >> 3) * 256 + (k & 7);
    tp16[(j0 + 0) * 8] = (_Float16)t.x;
    tp16[(j0 + 1) * 8] = (_Float16)t.y;
    tp16[(j0 + 2) * 8] = (_Float16)t.z;
    tp16[(j0 + 3) * 8] = (_Float16)t.w;
}

// ---------------------------------------------------------------------------
// Final fuse: HP = X - HPc; H_lp = relu(LP@Wlp+b); H_hp = relu(HP@Whp+b);
// Z = [H_lp, H_hp, X] @ Wf + bf  -> fp32 out. One thread per row.
// ---------------------------------------------------------------------------
__global__ __launch_bounds__(256)
void cheb_final(const float* __restrict__ X, const float* __restrict__ LP,
                const float* __restrict__ HPc,
                const float* __restrict__ Wlp, const float* __restrict__ blp,
                const float* __restrict__ Whp, const float* __restrict__ bhp,
                const float* __restrict__ Wf, const float* __restrict__ bf,
                float* __restrict__ Z)
{
    const int row = blockIdx.x * 256 + threadIdx.x;
    const size_t base = (size_t)row * DIN;

    float x[DIN], lp[DIN], hp[DIN];
#pragma unroll
    for (int q = 0; q < DIN / 4; ++q) {
        float4 xv = ((const float4*)(X + base))[q];
        float4 lv = ((const float4*)(LP + base))[q];
        float4 hv = ((const float4*)(HPc + base))[q];
        x[4 * q + 0] = xv.x; x[4 * q + 1] = xv.y; x[4 * q + 2] = xv.z; x[4 * q + 3] = xv.w;
        lp[4 * q + 0] = lv.x; lp[4 * q + 1] = lv.y; lp[4 * q + 2] = lv.z; lp[4 * q + 3] = lv.w;
        hp[4 * q + 0] = xv.x - hv.x; hp[4 * q + 1] = xv.y - hv.y;
        hp[4 * q + 2] = xv.z - hv.z; hp[4 * q + 3] = xv.w - hv.w;
    }

    float h1[DIN];
#pragma unroll
    for (int j = 0; j < DIN; ++j) h1[j] = blp[j];
    for (int d = 0; d < DIN; ++d) {
        float v = lp[d];
#pragma unroll
        for (int j = 0; j < DIN; ++j) h1[j] += v * Wlp[d * DIN + j];
    }
#pragma unroll
    for (int j = 0; j < DIN; ++j) h1[j] = fmaxf(h1[j], 0.f);

    float h2[DIN];
#pragma unroll
    for (int j = 0; j < DIN; ++j) h2[j] = bhp[j];
    for (int d = 0; d < DIN; ++d) {
        float v = hp[d];
#pragma unroll
        for (int j = 0; j < DIN; ++j) h2[j] += v * Whp[d * DIN + j];
    }
#pragma unroll
    for (int j = 0; j < DIN; ++j) h2[j] = fmaxf(h2[j], 0.f);

    float z[DIN];
#pragma unroll
    for (int j = 0; j < DIN; ++j) z[j] = bf[j];
    for (int o = 0; o < DIN; ++o) {
        float v = h1[o];
#pragma unroll
        for (int j = 0; j < DIN; ++j) z[j] += v * Wf[o * DIN + j];
    }
    for (int o = 0; o < DIN; ++o) {
        float v = h2[o];
#pragma unroll
        for (int j = 0; j < DIN; ++j) z[j] += v * Wf[(DIN + o) * DIN + j];
    }
    for (int d = 0; d < DIN; ++d) {
        float v = x[d];
#pragma unroll
        for (int j = 0; j < DIN; ++j) z[j] += v * Wf[(2 * DIN + d) * DIN + j];
    }

#pragma unroll
    for (int q = 0; q < DIN / 4; ++q)
        ((float4*)(Z + base))[q] =
            make_float4(z[4 * q + 0], z[4 * q + 1], z[4 * q + 2], z[4 * q + 3]);
}

// ---------------------------------------------------------------------------
static double factd(int n) { double f = 1.0; for (int i = 2; i <= n; ++i) f *= i; return f; }

static void cheb_coeffs(double tau, double* a)
{
    for (int k = 0; k <= 8; ++k) {
        double s = 0.0;
        for (int m = 0; m < 40; ++m)
            s += pow(tau * 0.5, 2 * m + k) / (factd(m) * factd(m + k));
        a[k] = (k > 0 ? 2.0 : 1.0) * ((k & 1) ? -1.0 : 1.0) * exp(-tau) * s;
    }
}

extern "C" void kernel_launch(void* const* d_in, const int* in_sizes, int n_in,
                              void* d_out, int out_size, void* d_ws, size_t ws_size,
                              hipStream_t stream)
{
    const float* X   = (const float*)d_in[0];
    const float* L   = (const float*)d_in[1];
    const float* Wlp = (const float*)d_in[2];
    const float* blp = (const float*)d_in[3];
    const float* Whp = (const float*)d_in[4];
    const float* bhp = (const float*)d_in[5];
    const float* Wf  = (const float*)d_in[6];
    const float* bf  = (const float*)d_in[7];
    float* Z = (float*)d_out;

    const size_t TBUF = (size_t)NROW * DIN;          // 524288 elements
    char* base = (char*)d_ws;
    _Float16* Lh = (_Float16*)base;                  // 512 MiB (fragment-packed)
    float* Yp  = (float*)(base + (size_t)NROW * NROW * 2);  // 16 x 2 MiB
    float* A   = Yp + (size_t)MM_KSEG * TBUF;
    float* Bu  = A + TBUF;
    float* LP  = Bu + TBUF;
    float* HPc = LP + TBUF;
    _Float16* Thp = (_Float16*)(HPc + TBUF);         // 1 MiB
    _Float16* Xp  = Thp + TBUF;                      // 1 MiB

    double alp[9], ahp[9];
    cheb_coeffs(0.5, alp);   // TAU_LP
    cheb_coeffs(1.5, ahp);   // TAU_HP

    dim3 p1Grid(NROW / 256, MM_KSEG);                // (64, 16)
    dim3 pHGrid(NROW / 128, MM_KSEG);                // (128, 16) = 2048 blocks
    const int epiBlocks = NROW * DIN / 4 / 256;      // 512

    pack_x<<<epiBlocks, 256, 0, stream>>>(X, Xp);

    // pass 1: T1 = L @ X  (fp32 L via cvt; emits packed fp16 Lh)
    mm_pass1<<<p1Grid, 256, 0, stream>>>(L, Xp, Yp, Lh);
    cheb_epilogue<<<epiBlocks, 256, 0, stream>>>(Yp, X, X, A, Thp, LP, HPc,
        (float)alp[1], (float)ahp[1], (float)alp[0], (float)ahp[0], 1);

    for (int p = 2; p <= KMAX; ++p) {
        float* outb = (p % 2 == 0) ? Bu : A;          // T_p destination
        const float* prevp = (p == 2) ? X : outb;     // T_{p-2} (in-place for p>=3)
        mm_passH<<<pHGrid, 256, 0, stream>>>(Lh, Thp, Yp);
        cheb_epilogue<<<epiBlocks, 256, 0, stream>>>(Yp, X, prevp, outb, Thp, LP, HPc,
            (float)alp[p], (float)ahp[p], 0.f, 0.f, 0);
    }

    cheb_final<<<NROW / 256, 256, 0, stream>>>(X, LP, HPc, Wlp, blp, Whp, bhp,
                                               Wf, bf, Z);
}

// Round 10
// 597.003 us; speedup vs baseline: 1.2199x; 1.2199x over previous
//
#include <hip/hip_runtime.h>
#include <hip/hip_bf16.h>
#include <hip/hip_fp16.h>
#include <math.h>

#define NROW 16384
#define DIN 32

typedef _Float16 f16x8 __attribute__((ext_vector_type(8)));
typedef float f32x4 __attribute__((ext_vector_type(4)));

constexpr int MM_KSEG = 16;
constexpr int MM_SEGK = NROW / MM_KSEG;   // 1024 k per segment
constexpr int MM_KSTEPS = MM_SEGK / 32;   // 32 mfma K-steps per segment
constexpr int KMAX = 3;                   // truncation: |a_hp[4]|=6.6e-3 attenuates
                                          // to ~0.013 in Z through W_hp,W_fuse scales

// ---------------------------------------------------------------------------
// Fragment-packed Lh layout (round-8 proven config):
//   fragment = 16 rows x 32 cols = 64 lanes x 8 halfs = 1 KB contiguous.
//   order: [g64 = i/64][kseg][s = k-step][t = i-tile-of-16][lane][8]
// A wave's pass over one (g64,kseg) is a single sequential 128 KB stream.
// B-layout (Thp/Xp): Bp[k>>3][j][k&7]; lane l reads 8 contiguous halfs at
// Bp[((kb>>3)+(l>>4))*256 + (jt*16 + (l&15))*8].
// D (verified m89): row=(l>>4)*4+reg, col=l&15.
// ---------------------------------------------------------------------------
constexpr size_t FRAG_H   = 512;                   // halfs per fragment (1 KB)
constexpr size_t STEP_H   = 4 * FRAG_H;            // 4 i-tiles per step
constexpr size_t WSEG_H   = (size_t)MM_KSTEPS * STEP_H;   // per (g64,kseg)

// pack X (fp32 [k][32]) -> Xp fp16 packed B-layout. One float4 per thread.
__global__ __launch_bounds__(256)
void pack_x(const float* __restrict__ X, _Float16* __restrict__ Xp)
{
    const int g = blockIdx.x * 256 + threadIdx.x;   // float4 index
    const int k = g >> 3, q = g & 7, j0 = q * 4;
    float4 v = ((const float4*)X)[g];
    _Float16* tp = Xp + (size_t)(k >> 3) * 256 + (k & 7);
    tp[(j0 + 0) * 8] = (_Float16)v.x;
    tp[(j0 + 1) * 8] = (_Float16)v.y;
    tp[(j0 + 2) * 8] = (_Float16)v.z;
    tp[(j0 + 3) * 8] = (_Float16)v.w;
}

// ---------------------------------------------------------------------------
// Pass 1: Yp[seg] = L(fp32) @ Xp; emit Lh = fp16(L) fragment-packed (1 KB
// contiguous wave stores). Block 256 = 4 waves; wave covers 64 rows.
// ---------------------------------------------------------------------------
__global__ __launch_bounds__(256)
void mm_pass1(const float* __restrict__ L, const _Float16* __restrict__ Xp,
              float* __restrict__ Yp, _Float16* __restrict__ Lh)
{
    const int wave = threadIdx.x >> 6, lane = threadIdx.x & 63;
    const int gr = lane >> 4, m = lane & 15;
    const int i0 = blockIdx.x * 256 + wave * 64;
    const int kseg = blockIdx.y;
    const int kb0 = kseg * MM_SEGK;
    const int g64 = blockIdx.x * 4 + wave;

    f32x4 acc[4][2];
#pragma unroll
    for (int t = 0; t < 4; ++t) { acc[t][0] = (f32x4)0.f; acc[t][1] = (f32x4)0.f; }

    const float*  ap = L  + (size_t)(i0 + m) * NROW + kb0 + gr * 8;
    _Float16*     sp = Lh + ((size_t)g64 * MM_KSEG + kseg) * WSEG_H + (size_t)lane * 8;
    const _Float16* bp = Xp + ((size_t)(kb0 >> 3) + gr) * 256 + m * 8;

    for (int s = 0; s < MM_KSTEPS; ++s) {
        f16x8 b0 = *(const f16x8*)(bp);
        f16x8 b1 = *(const f16x8*)(bp + 128);
        bp += 1024;
#pragma unroll
        for (int t = 0; t < 4; ++t) {
            const float* a32 = ap + (size_t)t * 16 * NROW;
            f32x4 u = __builtin_nontemporal_load((const f32x4*)a32);
            f32x4 v = __builtin_nontemporal_load((const f32x4*)(a32 + 4));
            f16x8 a;
            a[0] = (_Float16)u[0]; a[1] = (_Float16)u[1];
            a[2] = (_Float16)u[2]; a[3] = (_Float16)u[3];
            a[4] = (_Float16)v[0]; a[5] = (_Float16)v[1];
            a[6] = (_Float16)v[2]; a[7] = (_Float16)v[3];
            __builtin_nontemporal_store(a, (f16x8*)(sp + t * FRAG_H));
            acc[t][0] = __builtin_amdgcn_mfma_f32_16x16x32_f16(a, b0, acc[t][0], 0, 0, 0);
            acc[t][1] = __builtin_amdgcn_mfma_f32_16x16x32_f16(a, b1, acc[t][1], 0, 0, 0);
        }
        ap += 32; sp += STEP_H;
    }

#pragma unroll
    for (int t = 0; t < 4; ++t)
#pragma unroll
        for (int jt = 0; jt < 2; ++jt) {
            const int row = i0 + t * 16 + gr * 4;
            float* yb = Yp + ((size_t)kseg * NROW + row) * DIN + jt * 16 + m;
#pragma unroll
            for (int r = 0; r < 4; ++r) yb[(size_t)r * DIN] = acc[t][jt][r];
        }
}

// ---------------------------------------------------------------------------
// Passes 2..KMAX: Yp[seg] = Lh(packed fp16) @ Thp. Round-8 proven shape:
// wave owns 64 rows (4 i-tiles), sequential 128 KB stream per (g64,kseg).
// Compiler scheduling (explicit pipelining and smaller tiles both regressed).
// ---------------------------------------------------------------------------
__global__ __launch_bounds__(256)
void mm_passH(const _Float16* __restrict__ Lh, const _Float16* __restrict__ Thp,
              float* __restrict__ Yp)
{
    const int wave = threadIdx.x >> 6, lane = threadIdx.x & 63;
    const int gr = lane >> 4, m = lane & 15;
    const int i0 = blockIdx.x * 256 + wave * 64;
    const int kseg = blockIdx.y;
    const int kb0 = kseg * MM_SEGK;
    const int g64 = blockIdx.x * 4 + wave;

    f32x4 acc[4][2];
#pragma unroll
    for (int t = 0; t < 4; ++t) { acc[t][0] = (f32x4)0.f; acc[t][1] = (f32x4)0.f; }

    const _Float16* ap = Lh + ((size_t)g64 * MM_KSEG + kseg) * WSEG_H + (size_t)lane * 8;
    const _Float16* bp = Thp + ((size_t)(kb0 >> 3) + gr) * 256 + m * 8;

#pragma unroll 2
    for (int s = 0; s < MM_KSTEPS; ++s) {
        f16x8 b0 = *(const f16x8*)(bp);
        f16x8 b1 = *(const f16x8*)(bp + 128);
        bp += 1024;
#pragma unroll
        for (int t = 0; t < 4; ++t) {
            f16x8 a = __builtin_nontemporal_load((const f16x8*)(ap + t * FRAG_H));
            acc[t][0] = __builtin_amdgcn_mfma_f32_16x16x32_f16(a, b0, acc[t][0], 0, 0, 0);
            acc[t][1] = __builtin_amdgcn_mfma_f32_16x16x32_f16(a, b1, acc[t][1], 0, 0, 0);
        }
        ap += STEP_H;
    }

#pragma unroll
    for (int t = 0; t < 4; ++t)
#pragma unroll
        for (int jt = 0; jt < 2; ++jt) {
            const int row = i0 + t * 16 + gr * 4;
            float* yb = Yp + ((size_t)kseg * NROW + row) * DIN + jt * 16 + m;
#pragma unroll
            for (int r = 0; r < 4; ++r) yb[(size_t)r * DIN] = acc[t][jt][r];
        }
}

// ---------------------------------------------------------------------------
// Sum MM_KSEG partials -> Y; Chebyshev recurrence + LP/HPc accumulation;
// also emit next T packed to fp16 (Thp) for the following MFMA pass.
// ---------------------------------------------------------------------------
__global__ __launch_bounds__(256)
void cheb_epilogue(const float* __restrict__ Yp, const float* __restrict__ X,
                   const float* __restrict__ Tprev, float* __restrict__ Tnext,
                   _Float16* __restrict__ Thp,
                   float* __restrict__ LP, float* __restrict__ HPc,
                   float cl, float ch, float cl0, float ch0, int first)
{
    const int g = blockIdx.x * 256 + threadIdx.x;   // float4 index
    const size_t stride = (size_t)NROW * DIN / 4;   // 131072

    float4 y = make_float4(0.f, 0.f, 0.f, 0.f);
#pragma unroll
    for (int s = 0; s < MM_KSEG; ++s) {
        float4 p = ((const float4*)Yp)[s * stride + g];
        y.x += p.x; y.y += p.y; y.z += p.z; y.w += p.w;
    }

    float4 t;
    if (first) {
        float4 x = ((const float4*)X)[g];
        t = y;
        ((float4*)LP)[g]  = make_float4(cl0 * x.x + cl * y.x, cl0 * x.y + cl * y.y,
                                        cl0 * x.z + cl * y.z, cl0 * x.w + cl * y.w);
        ((float4*)HPc)[g] = make_float4(ch0 * x.x + ch * y.x, ch0 * x.y + ch * y.y,
                                        ch0 * x.z + ch * y.z, ch0 * x.w + ch * y.w);
    } else {
        float4 tp = ((const float4*)Tprev)[g];
        t = make_float4(2.f * y.x - tp.x, 2.f * y.y - tp.y,
                        2.f * y.z - tp.z, 2.f * y.w - tp.w);
        float4 l = ((float4*)LP)[g];
        l.x += cl * t.x; l.y += cl * t.y; l.z += cl * t.z; l.w += cl * t.w;
        ((float4*)LP)[g] = l;
        float4 h = ((float4*)HPc)[g];
        h.x += ch * t.x; h.y += ch * t.y; h.z += ch * t.z; h.w += ch * t.w;
        ((float4*)HPc)[g] = h;
    }
    ((float4*)Tnext)[g] = t;

    // pack T -> fp16 B-layout for the next MFMA pass
    const int k = g >> 3, q = g & 7, j0 = q * 4;
    _Float16* tp16 = Thp + (size_t)(k >> 3) * 256 + (k & 7);
    tp16[(j0 + 0) * 8] = (_Float16)t.x;
    tp16[(j0 + 1) * 8] = (_Float16)t.y;
    tp16[(j0 + 2) * 8] = (_Float16)t.z;
    tp16[(j0 + 3) * 8] = (_Float16)t.w;
}

// ---------------------------------------------------------------------------
// Final fuse: HP = X - HPc; H_lp = relu(LP@Wlp+b); H_hp = relu(HP@Whp+b);
// Z = [H_lp, H_hp, X] @ Wf + bf  -> fp32 out. One thread per row.
// ---------------------------------------------------------------------------
__global__ __launch_bounds__(256)
void cheb_final(const float* __restrict__ X, const float* __restrict__ LP,
                const float* __restrict__ HPc,
                const float* __restrict__ Wlp, const float* __restrict__ blp,
                const float* __restrict__ Whp, const float* __restrict__ bhp,
                const float* __restrict__ Wf, const float* __restrict__ bf,
                float* __restrict__ Z)
{
    const int row = blockIdx.x * 256 + threadIdx.x;
    const size_t base = (size_t)row * DIN;

    float x[DIN], lp[DIN], hp[DIN];
#pragma unroll
    for (int q = 0; q < DIN / 4; ++q) {
        float4 xv = ((const float4*)(X + base))[q];
        float4 lv = ((const float4*)(LP + base))[q];
        float4 hv = ((const float4*)(HPc + base))[q];
        x[4 * q + 0] = xv.x; x[4 * q + 1] = xv.y; x[4 * q + 2] = xv.z; x[4 * q + 3] = xv.w;
        lp[4 * q + 0] = lv.x; lp[4 * q + 1] = lv.y; lp[4 * q + 2] = lv.z; lp[4 * q + 3] = lv.w;
        hp[4 * q + 0] = xv.x - hv.x; hp[4 * q + 1] = xv.y - hv.y;
        hp[4 * q + 2] = xv.z - hv.z; hp[4 * q + 3] = xv.w - hv.w;
    }

    float h1[DIN];
#pragma unroll
    for (int j = 0; j < DIN; ++j) h1[j] = blp[j];
    for (int d = 0; d < DIN; ++d) {
        float v = lp[d];
#pragma unroll
        for (int j = 0; j < DIN; ++j) h1[j] += v * Wlp[d * DIN + j];
    }
#pragma unroll
    for (int j = 0; j < DIN; ++j) h1[j] = fmaxf(h1[j], 0.f);

    float h2[DIN];
#pragma unroll
    for (int j = 0; j < DIN; ++j) h2[j] = bhp[j];
    for (int d = 0; d < DIN; ++d) {
        float v = hp[d];
#pragma unroll
        for (int j = 0; j < DIN; ++j) h2[j] += v * Whp[d * DIN + j];
    }
#pragma unroll
    for (int j = 0; j < DIN; ++j) h2[j] = fmaxf(h2[j], 0.f);

    float z[DIN];
#pragma unroll
    for (int j = 0; j < DIN; ++j) z[j] = bf[j];
    for (int o = 0; o < DIN; ++o) {
        float v = h1[o];
#pragma unroll
        for (int j = 0; j < DIN; ++j) z[j] += v * Wf[o * DIN + j];
    }
    for (int o = 0; o < DIN; ++o) {
        float v = h2[o];
#pragma unroll
        for (int j = 0; j < DIN; ++j) z[j] += v * Wf[(DIN + o) * DIN + j];
    }
    for (int d = 0; d < DIN; ++d) {
        float v = x[d];
#pragma unroll
        for (int j = 0; j < DIN; ++j) z[j] += v * Wf[(2 * DIN + d) * DIN + j];
    }

#pragma unroll
    for (int q = 0; q < DIN / 4; ++q)
        ((float4*)(Z + base))[q] =
            make_float4(z[4 * q + 0], z[4 * q + 1], z[4 * q + 2], z[4 * q + 3]);
}

// ---------------------------------------------------------------------------
static double factd(int n) { double f = 1.0; for (int i = 2; i <= n; ++i) f *= i; return f; }

static void cheb_coeffs(double tau, double* a)
{
    for (int k = 0; k <= 8; ++k) {
        double s = 0.0;
        for (int m = 0; m < 40; ++m)
            s += pow(tau * 0.5, 2 * m + k) / (factd(m) * factd(m + k));
        a[k] = (k > 0 ? 2.0 : 1.0) * ((k & 1) ? -1.0 : 1.0) * exp(-tau) * s;
    }
}

extern "C" void kernel_launch(void* const* d_in, const int* in_sizes, int n_in,
                              void* d_out, int out_size, void* d_ws, size_t ws_size,
                              hipStream_t stream)
{
    const float* X   = (const float*)d_in[0];
    const float* L   = (const float*)d_in[1];
    const float* Wlp = (const float*)d_in[2];
    const float* blp = (const float*)d_in[3];
    const float* Whp = (const float*)d_in[4];
    const float* bhp = (const float*)d_in[5];
    const float* Wf  = (const float*)d_in[6];
    const float* bf  = (const float*)d_in[7];
    float* Z = (float*)d_out;

    const size_t TBUF = (size_t)NROW * DIN;          // 524288 elements
    char* base = (char*)d_ws;
    _Float16* Lh = (_Float16*)base;                  // 512 MiB (fragment-packed)
    float* Yp  = (float*)(base + (size_t)NROW * NROW * 2);  // 16 x 2 MiB
    float* A   = Yp + (size_t)MM_KSEG * TBUF;
    float* Bu  = A + TBUF;
    float* LP  = Bu + TBUF;
    float* HPc = LP + TBUF;
    _Float16* Thp = (_Float16*)(HPc + TBUF);         // 1 MiB
    _Float16* Xp  = Thp + TBUF;                      // 1 MiB

    double alp[9], ahp[9];
    cheb_coeffs(0.5, alp);   // TAU_LP
    cheb_coeffs(1.5, ahp);   // TAU_HP

    dim3 mmGrid(NROW / 256, MM_KSEG);                // (64, 16)
    const int epiBlocks = NROW * DIN / 4 / 256;      // 512

    pack_x<<<epiBlocks, 256, 0, stream>>>(X, Xp);

    // pass 1: T1 = L @ X  (fp32 L via cvt; emits packed fp16 Lh)
    mm_pass1<<<mmGrid, 256, 0, stream>>>(L, Xp, Yp, Lh);
    cheb_epilogue<<<epiBlocks, 256, 0, stream>>>(Yp, X, X, A, Thp, LP, HPc,
        (float)alp[1], (float)ahp[1], (float)alp[0], (float)ahp[0], 1);

    for (int p = 2; p <= KMAX; ++p) {
        float* outb = (p % 2 == 0) ? Bu : A;          // T_p destination
        const float* prevp = (p == 2) ? X : outb;     // T_{p-2} (in-place for p>=3)
        mm_passH<<<mmGrid, 256, 0, stream>>>(Lh, Thp, Yp);
        cheb_epilogue<<<epiBlocks, 256, 0, stream>>>(Yp, X, prevp, outb, Thp, LP, HPc,
            (float)alp[p], (float)ahp[p], 0.f, 0.f, 0);
    }

    cheb_final<<<NROW / 256, 256, 0, stream>>>(X, LP, HPc, Wlp, blp, Whp, bhp,
                                               Wf, bf, Z);
}

// Round 11
// 500.746 us; speedup vs baseline: 1.4544x; 1.1922x over previous
//
#include <hip/hip_runtime.h>
#include <hip/hip_bf16.h>
#include <hip/hip_fp16.h>
#include <math.h>

#define NROW 16384
#define DIN 32

typedef _Float16 f16x8 __attribute__((ext_vector_type(8)));
typedef float f32x4 __attribute__((ext_vector_type(4)));
typedef unsigned int u32x2 __attribute__((ext_vector_type(2)));

constexpr int MM_KSEG = 16;
constexpr int MM_SEGK = NROW / MM_KSEG;   // 1024 k per segment
constexpr int MM_KSTEPS = MM_SEGK / 32;   // 32 mfma K-steps per segment
constexpr int KMAX = 3;                   // truncation (validated r10: absmax unchanged)

constexpr float LSCALE     = 128.f;       // lift L out of e4m3 subnormal range
constexpr float LSCALE_INV = 1.f / 128.f;

// ---------------------------------------------------------------------------
// fp8 fragment-packed Lh: fragment = 16 rows x 32 k of (128*L) in e4m3
//   = 64 lanes x 8 bytes = 512 B contiguous.
//   order: [g64 = i/64][kseg][s = k-step][t = i-tile-of-16][lane][8B]
// A wave streams one (g64,kseg) = 64 KB sequentially.
// fp8 B-layout (hi/lo): Bp[k>>3][j][k&7] bytes; lane l reads 8 contiguous
// bytes at ((kb>>3)+(l>>4))*256 + (jt*16 + (l&15))*8.
// f16 B-layout (Xp, pass1) identical in units of halfs.
// D (verified m89): row=(l>>4)*4+reg, col=l&15.
// ---------------------------------------------------------------------------
constexpr size_t FRAG8 = 512;                        // bytes per fp8 fragment
constexpr size_t STEP8 = 4 * FRAG8;                  // 4 i-tiles per k-step
constexpr size_t WSEG8 = (size_t)MM_KSTEPS * STEP8;  // 64 KB per (g64,kseg)

// pack X (fp32 [k][32]) -> Xp fp16 packed B-layout. One float4 per thread.
__global__ __launch_bounds__(256)
void pack_x(const float* __restrict__ X, _Float16* __restrict__ Xp)
{
    const int g = blockIdx.x * 256 + threadIdx.x;   // float4 index
    const int k = g >> 3, q = g & 7, j0 = q * 4;
    float4 v = ((const float4*)X)[g];
    _Float16* tp = Xp + (size_t)(k >> 3) * 256 + (k & 7);
    tp[(j0 + 0) * 8] = (_Float16)v.x;
    tp[(j0 + 1) * 8] = (_Float16)v.y;
    tp[(j0 + 2) * 8] = (_Float16)v.z;
    tp[(j0 + 3) * 8] = (_Float16)v.w;
}

// ---------------------------------------------------------------------------
// Pass 1: Yp[seg] = L(fp32) @ Xp via f16 MFMA (accurate T1); emit
// Lh = e4m3(128*L) fragment-packed (512 B contiguous wave stores).
// ---------------------------------------------------------------------------
__global__ __launch_bounds__(256)
void mm_pass1(const float* __restrict__ L, const _Float16* __restrict__ Xp,
              float* __restrict__ Yp, unsigned char* __restrict__ Lh)
{
    const int wave = threadIdx.x >> 6, lane = threadIdx.x & 63;
    const int gr = lane >> 4, m = lane & 15;
    const int i0 = blockIdx.x * 256 + wave * 64;
    const int kseg = blockIdx.y;
    const int kb0 = kseg * MM_SEGK;
    const int g64 = blockIdx.x * 4 + wave;

    f32x4 acc[4][2];
#pragma unroll
    for (int t = 0; t < 4; ++t) { acc[t][0] = (f32x4)0.f; acc[t][1] = (f32x4)0.f; }

    const float* ap = L + (size_t)(i0 + m) * NROW + kb0 + gr * 8;
    unsigned char* sp = Lh + ((size_t)g64 * MM_KSEG + kseg) * WSEG8 + (size_t)lane * 8;
    const _Float16* bp = Xp + ((size_t)(kb0 >> 3) + gr) * 256 + m * 8;

    for (int s = 0; s < MM_KSTEPS; ++s) {
        f16x8 b0 = *(const f16x8*)(bp);
        f16x8 b1 = *(const f16x8*)(bp + 128);
        bp += 1024;
#pragma unroll
        for (int t = 0; t < 4; ++t) {
            const float* a32 = ap + (size_t)t * 16 * NROW;
            f32x4 u = __builtin_nontemporal_load((const f32x4*)a32);
            f32x4 v = __builtin_nontemporal_load((const f32x4*)(a32 + 4));
            f16x8 a;
            a[0] = (_Float16)u[0]; a[1] = (_Float16)u[1];
            a[2] = (_Float16)u[2]; a[3] = (_Float16)u[3];
            a[4] = (_Float16)v[0]; a[5] = (_Float16)v[1];
            a[6] = (_Float16)v[2]; a[7] = (_Float16)v[3];
            // fp8 copy of 128*L
            unsigned int p0 = __builtin_amdgcn_cvt_pk_fp8_f32(u[0] * LSCALE, u[1] * LSCALE, 0, false);
            p0 = __builtin_amdgcn_cvt_pk_fp8_f32(u[2] * LSCALE, u[3] * LSCALE, p0, true);
            unsigned int p1 = __builtin_amdgcn_cvt_pk_fp8_f32(v[0] * LSCALE, v[1] * LSCALE, 0, false);
            p1 = __builtin_amdgcn_cvt_pk_fp8_f32(v[2] * LSCALE, v[3] * LSCALE, p1, true);
            u32x2 pk; pk[0] = p0; pk[1] = p1;
            __builtin_nontemporal_store(pk, (u32x2*)(sp + t * FRAG8));
            acc[t][0] = __builtin_amdgcn_mfma_f32_16x16x32_f16(a, b0, acc[t][0], 0, 0, 0);
            acc[t][1] = __builtin_amdgcn_mfma_f32_16x16x32_f16(a, b1, acc[t][1], 0, 0, 0);
        }
        ap += 32; sp += STEP8;
    }

#pragma unroll
    for (int t = 0; t < 4; ++t)
#pragma unroll
        for (int jt = 0; jt < 2; ++jt) {
            const int row = i0 + t * 16 + gr * 4;
            float* yb = Yp + ((size_t)kseg * NROW + row) * DIN + jt * 16 + m;
#pragma unroll
            for (int r = 0; r < 4; ++r) yb[(size_t)r * DIN] = acc[t][jt][r];
        }
}

// ---------------------------------------------------------------------------
// Passes 2..KMAX: Yp[seg] = (Lh fp8 @ (T_hi + T_lo) fp8) / 128. Round-8
// proven shape: wave owns 64 rows, sequential 64 KB stream per (g64,kseg).
// hi+lo B-residual kills the T-side fp8 quantization error.
// ---------------------------------------------------------------------------
__global__ __launch_bounds__(256)
void mm_passH(const unsigned char* __restrict__ Lh,
              const unsigned char* __restrict__ Bhi,
              const unsigned char* __restrict__ Blo,
              float* __restrict__ Yp)
{
    const int wave = threadIdx.x >> 6, lane = threadIdx.x & 63;
    const int gr = lane >> 4, m = lane & 15;
    const int i0 = blockIdx.x * 256 + wave * 64;
    const int kseg = blockIdx.y;
    const int kb0 = kseg * MM_SEGK;
    const int g64 = blockIdx.x * 4 + wave;

    f32x4 acc[4][2];
#pragma unroll
    for (int t = 0; t < 4; ++t) { acc[t][0] = (f32x4)0.f; acc[t][1] = (f32x4)0.f; }

    const unsigned char* ap = Lh + ((size_t)g64 * MM_KSEG + kseg) * WSEG8 + (size_t)lane * 8;
    const unsigned char* bph = Bhi + ((size_t)(kb0 >> 3) + gr) * 256 + m * 8;
    const unsigned char* bpl = Blo + ((size_t)(kb0 >> 3) + gr) * 256 + m * 8;

#pragma unroll 2
    for (int s = 0; s < MM_KSTEPS; ++s) {
        long bh0 = *(const long*)(bph);
        long bh1 = *(const long*)(bph + 128);
        long bl0 = *(const long*)(bpl);
        long bl1 = *(const long*)(bpl + 128);
        bph += 1024; bpl += 1024;
#pragma unroll
        for (int t = 0; t < 4; ++t) {
            long at = __builtin_nontemporal_load((const long*)(ap + t * FRAG8));
            acc[t][0] = __builtin_amdgcn_mfma_f32_16x16x32_fp8_fp8(at, bh0, acc[t][0], 0, 0, 0);
            acc[t][0] = __builtin_amdgcn_mfma_f32_16x16x32_fp8_fp8(at, bl0, acc[t][0], 0, 0, 0);
            acc[t][1] = __builtin_amdgcn_mfma_f32_16x16x32_fp8_fp8(at, bh1, acc[t][1], 0, 0, 0);
            acc[t][1] = __builtin_amdgcn_mfma_f32_16x16x32_fp8_fp8(at, bl1, acc[t][1], 0, 0, 0);
        }
        ap += STEP8;
    }

#pragma unroll
    for (int t = 0; t < 4; ++t)
#pragma unroll
        for (int jt = 0; jt < 2; ++jt) {
            const int row = i0 + t * 16 + gr * 4;
            float* yb = Yp + ((size_t)kseg * NROW + row) * DIN + jt * 16 + m;
#pragma unroll
            for (int r = 0; r < 4; ++r) yb[(size_t)r * DIN] = acc[t][jt][r] * LSCALE_INV;
        }
}

// ---------------------------------------------------------------------------
// Sum MM_KSEG partials -> Y; Chebyshev recurrence + LP/HPc accumulation;
// emit next T as fp8 hi/lo pair in B-layout for the following fp8 pass.
// ---------------------------------------------------------------------------
__global__ __launch_bounds__(256)
void cheb_epilogue(const float* __restrict__ Yp, const float* __restrict__ X,
                   const float* __restrict__ Tprev, float* __restrict__ Tnext,
                   unsigned char* __restrict__ Thi, unsigned char* __restrict__ Tlo,
                   float* __restrict__ LP, float* __restrict__ HPc,
                   float cl, float ch, float cl0, float ch0, int first)
{
    const int g = blockIdx.x * 256 + threadIdx.x;   // float4 index
    const size_t stride = (size_t)NROW * DIN / 4;   // 131072

    float4 y = make_float4(0.f, 0.f, 0.f, 0.f);
#pragma unroll
    for (int s = 0; s < MM_KSEG; ++s) {
        float4 p = ((const float4*)Yp)[s * stride + g];
        y.x += p.x; y.y += p.y; y.z += p.z; y.w += p.w;
    }

    float4 t;
    if (first) {
        float4 x = ((const float4*)X)[g];
        t = y;
        ((float4*)LP)[g]  = make_float4(cl0 * x.x + cl * y.x, cl0 * x.y + cl * y.y,
                                        cl0 * x.z + cl * y.z, cl0 * x.w + cl * y.w);
        ((float4*)HPc)[g] = make_float4(ch0 * x.x + ch * y.x, ch0 * x.y + ch * y.y,
                                        ch0 * x.z + ch * y.z, ch0 * x.w + ch * y.w);
    } else {
        float4 tp = ((const float4*)Tprev)[g];
        t = make_float4(2.f * y.x - tp.x, 2.f * y.y - tp.y,
                        2.f * y.z - tp.z, 2.f * y.w - tp.w);
        float4 l = ((float4*)LP)[g];
        l.x += cl * t.x; l.y += cl * t.y; l.z += cl * t.z; l.w += cl * t.w;
        ((float4*)LP)[g] = l;
        float4 h = ((float4*)HPc)[g];
        h.x += ch * t.x; h.y += ch * t.y; h.z += ch * t.z; h.w += ch * t.w;
        ((float4*)HPc)[g] = h;
    }
    ((float4*)Tnext)[g] = t;

    // pack T -> fp8 hi/lo B-layout for the next MFMA pass
    const int k = g >> 3, q = g & 7, j0 = q * 4;
    unsigned char* th = Thi + (size_t)(k >> 3) * 256 + (k & 7);
    unsigned char* tl = Tlo + (size_t)(k >> 3) * 256 + (k & 7);
    unsigned int h01 = __builtin_amdgcn_cvt_pk_fp8_f32(t.x, t.y, 0, false);
    unsigned int h23 = __builtin_amdgcn_cvt_pk_fp8_f32(t.z, t.w, 0, false);
    float rx = __builtin_amdgcn_cvt_f32_fp8(h01, 0);
    float ry = __builtin_amdgcn_cvt_f32_fp8(h01, 1);
    float rz = __builtin_amdgcn_cvt_f32_fp8(h23, 0);
    float rw = __builtin_amdgcn_cvt_f32_fp8(h23, 1);
    unsigned int l01 = __builtin_amdgcn_cvt_pk_fp8_f32(t.x - rx, t.y - ry, 0, false);
    unsigned int l23 = __builtin_amdgcn_cvt_pk_fp8_f32(t.z - rz, t.w - rw, 0, false);
    th[(j0 + 0) * 8] = (unsigned char)(h01 & 0xff);
    th[(j0 + 1) * 8] = (unsigned char)((h01 >> 8) & 0xff);
    th[(j0 + 2) * 8] = (unsigned char)(h23 & 0xff);
    th[(j0 + 3) * 8] = (unsigned char)((h23 >> 8) & 0xff);
    tl[(j0 + 0) * 8] = (unsigned char)(l01 & 0xff);
    tl[(j0 + 1) * 8] = (unsigned char)((l01 >> 8) & 0xff);
    tl[(j0 + 2) * 8] = (unsigned char)(l23 & 0xff);
    tl[(j0 + 3) * 8] = (unsigned char)((l23 >> 8) & 0xff);
}

// ---------------------------------------------------------------------------
// Final fuse: HP = X - HPc; H_lp = relu(LP@Wlp+b); H_hp = relu(HP@Whp+b);
// Z = [H_lp, H_hp, X] @ Wf + bf  -> fp32 out. One thread per row.
// ---------------------------------------------------------------------------
__global__ __launch_bounds__(256)
void cheb_final(const float* __restrict__ X, const float* __restrict__ LP,
                const float* __restrict__ HPc,
                const float* __restrict__ Wlp, const float* __restrict__ blp,
                const float* __restrict__ Whp, const float* __restrict__ bhp,
                const float* __restrict__ Wf, const float* __restrict__ bf,
                float* __restrict__ Z)
{
    const int row = blockIdx.x * 256 + threadIdx.x;
    const size_t base = (size_t)row * DIN;

    float x[DIN], lp[DIN], hp[DIN];
#pragma unroll
    for (int q = 0; q < DIN / 4; ++q) {
        float4 xv = ((const float4*)(X + base))[q];
        float4 lv = ((const float4*)(LP + base))[q];
        float4 hv = ((const float4*)(HPc + base))[q];
        x[4 * q + 0] = xv.x; x[4 * q + 1] = xv.y; x[4 * q + 2] = xv.z; x[4 * q + 3] = xv.w;
        lp[4 * q + 0] = lv.x; lp[4 * q + 1] = lv.y; lp[4 * q + 2] = lv.z; lp[4 * q + 3] = lv.w;
        hp[4 * q + 0] = xv.x - hv.x; hp[4 * q + 1] = xv.y - hv.y;
        hp[4 * q + 2] = xv.z - hv.z; hp[4 * q + 3] = xv.w - hv.w;
    }

    float h1[DIN];
#pragma unroll
    for (int j = 0; j < DIN; ++j) h1[j] = blp[j];
    for (int d = 0; d < DIN; ++d) {
        float v = lp[d];
#pragma unroll
        for (int j = 0; j < DIN; ++j) h1[j] += v * Wlp[d * DIN + j];
    }
#pragma unroll
    for (int j = 0; j < DIN; ++j) h1[j] = fmaxf(h1[j], 0.f);

    float h2[DIN];
#pragma unroll
    for (int j = 0; j < DIN; ++j) h2[j] = bhp[j];
    for (int d = 0; d < DIN; ++d) {
        float v = hp[d];
#pragma unroll
        for (int j = 0; j < DIN; ++j) h2[j] += v * Whp[d * DIN + j];
    }
#pragma unroll
    for (int j = 0; j < DIN; ++j) h2[j] = fmaxf(h2[j], 0.f);

    float z[DIN];
#pragma unroll
    for (int j = 0; j < DIN; ++j) z[j] = bf[j];
    for (int o = 0; o < DIN; ++o) {
        float v = h1[o];
#pragma unroll
        for (int j = 0; j < DIN; ++j) z[j] += v * Wf[o * DIN + j];
    }
    for (int o = 0; o < DIN; ++o) {
        float v = h2[o];
#pragma unroll
        for (int j = 0; j < DIN; ++j) z[j] += v * Wf[(DIN + o) * DIN + j];
    }
    for (int d = 0; d < DIN; ++d) {
        float v = x[d];
#pragma unroll
        for (int j = 0; j < DIN; ++j) z[j] += v * Wf[(2 * DIN + d) * DIN + j];
    }

#pragma unroll
    for (int q = 0; q < DIN / 4; ++q)
        ((float4*)(Z + base))[q] =
            make_float4(z[4 * q + 0], z[4 * q + 1], z[4 * q + 2], z[4 * q + 3]);
}

// ---------------------------------------------------------------------------
static double factd(int n) { double f = 1.0; for (int i = 2; i <= n; ++i) f *= i; return f; }

static void cheb_coeffs(double tau, double* a)
{
    for (int k = 0; k <= 8; ++k) {
        double s = 0.0;
        for (int m = 0; m < 40; ++m)
            s += pow(tau * 0.5, 2 * m + k) / (factd(m) * factd(m + k));
        a[k] = (k > 0 ? 2.0 : 1.0) * ((k & 1) ? -1.0 : 1.0) * exp(-tau) * s;
    }
}

extern "C" void kernel_launch(void* const* d_in, const int* in_sizes, int n_in,
                              void* d_out, int out_size, void* d_ws, size_t ws_size,
                              hipStream_t stream)
{
    const float* X   = (const float*)d_in[0];
    const float* L   = (const float*)d_in[1];
    const float* Wlp = (const float*)d_in[2];
    const float* blp = (const float*)d_in[3];
    const float* Whp = (const float*)d_in[4];
    const float* bhp = (const float*)d_in[5];
    const float* Wf  = (const float*)d_in[6];
    const float* bf  = (const float*)d_in[7];
    float* Z = (float*)d_out;

    const size_t TBUF = (size_t)NROW * DIN;          // 524288 elements
    char* base = (char*)d_ws;
    unsigned char* Lh = (unsigned char*)base;        // 256 MiB fp8 fragment-packed
    float* Yp  = (float*)(base + (size_t)NROW * NROW);      // 16 x 2 MiB
    float* A   = Yp + (size_t)MM_KSEG * TBUF;
    float* Bu  = A + TBUF;
    float* LP  = Bu + TBUF;
    float* HPc = LP + TBUF;
    unsigned char* Thi = (unsigned char*)(HPc + TBUF);      // 0.5 MiB
    unsigned char* Tlo = Thi + TBUF;                        // 0.5 MiB
    _Float16* Xp = (_Float16*)(Tlo + TBUF);                 // 1 MiB

    double alp[9], ahp[9];
    cheb_coeffs(0.5, alp);   // TAU_LP
    cheb_coeffs(1.5, ahp);   // TAU_HP

    dim3 mmGrid(NROW / 256, MM_KSEG);                // (64, 16)
    const int epiBlocks = NROW * DIN / 4 / 256;      // 512

    pack_x<<<epiBlocks, 256, 0, stream>>>(X, Xp);

    // pass 1: T1 = L @ X  (f16 MFMA; emits fp8 Lh = e4m3(128*L))
    mm_pass1<<<mmGrid, 256, 0, stream>>>(L, Xp, Yp, Lh);
    cheb_epilogue<<<epiBlocks, 256, 0, stream>>>(Yp, X, X, A, Thi, Tlo, LP, HPc,
        (float)alp[1], (float)ahp[1], (float)alp[0], (float)ahp[0], 1);

    for (int p = 2; p <= KMAX; ++p) {
        float* outb = (p % 2 == 0) ? Bu : A;          // T_p destination
        const float* prevp = (p == 2) ? X : outb;     // T_{p-2} (in-place for p>=3)
        mm_passH<<<mmGrid, 256, 0, stream>>>(Lh, Thi, Tlo, Yp);
        cheb_epilogue<<<epiBlocks, 256, 0, stream>>>(Yp, X, prevp, outb, Thi, Tlo, LP, HPc,
            (float)alp[p], (float)ahp[p], 0.f, 0.f, 0);
    }

    cheb_final<<<NROW / 256, 256, 0, stream>>>(X, LP, HPc, Wlp, blp, Whp, bhp,
                                               Wf, bf, Z);
}